// Round 1
// baseline (1866.851 us; speedup 1.0000x reference)
//
#include <hip/hip_runtime.h>
#include <math.h>

// Problem constants (reference: B=16, D=256, H=32, W=32, K=4096)
#define BD  16
#define DD  256
#define HWD 1024      // H*W
#define NTOK 16384    // B*H*W
#define KK  4096
#define TT  64        // tokens per block
#define KGRP 16       // k's accumulated per register block

// ---------------------------------------------------------------------------
// Kernel 1: codebook squared norms. One wave per codebook row.
// ---------------------------------------------------------------------------
__global__ __launch_bounds__(256) void vq_cnorm(const float* __restrict__ cb,
                                                float* __restrict__ cnorm) {
    int k = (blockIdx.x * 256 + threadIdx.x) >> 6;   // 1024 blocks -> k in [0,4096)
    int lane = threadIdx.x & 63;
    float4 v = reinterpret_cast<const float4*>(cb)[k * 64 + lane];
    float s = v.x * v.x + v.y * v.y + v.z * v.z + v.w * v.w;
    #pragma unroll
    for (int off = 32; off > 0; off >>= 1) s += __shfl_xor(s, off, 64);
    if (lane == 0) cnorm[k] = s;
}

// ---------------------------------------------------------------------------
// Kernel 2: distances + per-(block,phase) argmin candidates.
// Block = 256 threads = 4 waves, owns 64 tokens (lane == token).
// grid.y = 2 phases split the K range -> 512 blocks -> 2 blocks/CU.
// x tile staged in LDS as float2 d-pairs [128][64 tokens]; codebook read via
// wave-uniform addresses -> scalar loads (constant cache), 1 SGPR/VALU op.
// ---------------------------------------------------------------------------
__global__ __launch_bounds__(256) void vq_dist(const float* __restrict__ x,
                                               const float* __restrict__ cb,
                                               const float* __restrict__ cnorm,
                                               float* __restrict__ cand_d,
                                               int* __restrict__ cand_k) {
    const int blk = blockIdx.x;
    const int phase = blockIdx.y;
    const int tid = threadIdx.x;
    const int wid = tid >> 6, lane = tid & 63;
    const int b = blk >> 4;
    const int hw0 = (blk & 15) << 6;

    __shared__ alignas(16) float xs[DD * TT];   // 64 KB, layout: [d/2][tok][2]
    __shared__ float bd_s[4][TT];
    __shared__ int   bk_s[4][TT];

    // Stage x tile: x[b, d, hw0+i] -> xs[(d/2)*128 + i*2 + (d&1)]
    const float* xb = x + b * (DD * HWD) + hw0;
    #pragma unroll 4
    for (int it = 0; it < 64; ++it) {
        int e = it * 256 + tid;
        int d = e >> 6, i = e & 63;
        xs[(d >> 1) * 128 + i * 2 + (d & 1)] = xb[d * HWD + i];
    }
    __syncthreads();

    const float2* xs2 = reinterpret_cast<const float2*>(xs) + lane;

    float best = HUGE_VALF;
    int bestk = 0;
    // Wave-uniform k-group walk: lanes are tokens; kk/d loops uniform -> s_load
    for (int g = phase * 4 + wid; g < KK / KGRP; g += 8) {
        const int k0 = g * KGRP;
        const float* __restrict__ cg = cb + k0 * DD;
        float acc[KGRP];
        #pragma unroll
        for (int kk = 0; kk < KGRP; ++kk) acc[kk] = 0.f;
        #pragma unroll 2
        for (int d2 = 0; d2 < DD / 2; ++d2) {
            float2 xv = xs2[d2 * 64];
            #pragma unroll
            for (int kk = 0; kk < KGRP; ++kk) {
                acc[kk] = fmaf(xv.x, cg[kk * DD + d2 * 2], acc[kk]);
                acc[kk] = fmaf(xv.y, cg[kk * DD + d2 * 2 + 1], acc[kk]);
            }
        }
        #pragma unroll
        for (int kk = 0; kk < KGRP; ++kk) {
            // d2 = ||c||^2 - 2 x.c   (||x||^2 constant per token, argmin-invariant)
            float dv = fmaf(-2.0f, acc[kk], cnorm[k0 + kk]);
            if (dv < best) { best = dv; bestk = k0 + kk; }   // k ascending -> first-min
        }
    }

    bd_s[wid][lane] = best;
    bk_s[wid][lane] = bestk;
    __syncthreads();

    if (tid < 64) {
        float bd = bd_s[0][lane];
        int   bk = bk_s[0][lane];
        #pragma unroll
        for (int w = 1; w < 4; ++w) {
            float dd = bd_s[w][lane];
            int   kw = bk_s[w][lane];
            if (dd < bd || (dd == bd && kw < bk)) { bd = dd; bk = kw; }
        }
        int n = blk * TT + lane;
        cand_d[phase * NTOK + n] = bd;
        cand_k[phase * NTOK + n] = bk;
    }
}

// ---------------------------------------------------------------------------
// Kernel 3: combine the 2 phase candidates, gather codebook rows, write
// [B, D, H, W] with an LDS transpose so reads AND writes are coalesced.
// ---------------------------------------------------------------------------
__global__ __launch_bounds__(256) void vq_gather(const float* __restrict__ cb,
                                                 const float* __restrict__ cand_d,
                                                 const int* __restrict__ cand_k,
                                                 float* __restrict__ out) {
    const int blk = blockIdx.x;
    const int tid = threadIdx.x;
    const int b = blk >> 4;
    const int hw0 = (blk & 15) << 6;

    __shared__ int   bks[TT];
    __shared__ float ts[TT][65];   // +1 pad: transposed read 2-way (free)

    if (tid < 64) {
        int n = blk * TT + tid;
        float d0 = cand_d[n];
        int   k0 = cand_k[n];
        float d1 = cand_d[NTOK + n];
        int   k1 = cand_k[NTOK + n];
        bks[tid] = (d1 < d0 || (d1 == d0 && k1 < k0)) ? k1 : k0;
    }
    __syncthreads();

    const int rr = tid >> 6;   // 0..3
    const int j  = tid & 63;
    float* ob = out + b * (DD * HWD) + hw0;
    #pragma unroll
    for (int c = 0; c < 4; ++c) {
        const int d0 = c << 6;
        #pragma unroll 4
        for (int it = 0; it < 16; ++it) {
            int tok = it * 4 + rr;
            ts[tok][j] = cb[bks[tok] * DD + d0 + j];   // coalesced along d
        }
        __syncthreads();
        #pragma unroll 4
        for (int it = 0; it < 16; ++it) {
            int dl = it * 4 + rr;
            ob[(d0 + dl) * HWD + j] = ts[j][dl];       // coalesced along hw
        }
        __syncthreads();
    }
}

// ---------------------------------------------------------------------------
extern "C" void kernel_launch(void* const* d_in, const int* in_sizes, int n_in,
                              void* d_out, int out_size, void* d_ws, size_t ws_size,
                              hipStream_t stream) {
    const float* x  = (const float*)d_in[0];   // [16,256,32,32] f32
    const float* cb = (const float*)d_in[1];   // [4096,256] f32
    float* out = (float*)d_out;                // [16,256,32,32] f32

    float* ws_f   = (float*)d_ws;
    float* cnorm  = ws_f;                 // 4096 floats
    float* cand_d = ws_f + 4096;          // 2 * 16384 floats
    int*   cand_k = (int*)(ws_f + 4096 + 2 * NTOK);   // 2 * 16384 ints

    vq_cnorm<<<dim3(KK / 4), dim3(256), 0, stream>>>(cb, cnorm);
    vq_dist<<<dim3(NTOK / TT, 2), dim3(256), 0, stream>>>(x, cb, cnorm, cand_d, cand_k);
    vq_gather<<<dim3(NTOK / TT), dim3(256), 0, stream>>>(cb, cand_d, cand_k, out);
}

// Round 2
// 649.910 us; speedup vs baseline: 2.8725x; 2.8725x over previous
//
#include <hip/hip_runtime.h>
#include <math.h>

// Problem constants (reference: B=16, D=256, H=32, W=32, K=4096)
#define DD   256
#define HWD  1024      // H*W
#define NTOK 16384     // B*H*W
#define KK   4096
#define TT   64        // tokens per dist block
#define KGRP 16        // codebook rows per register block
#define NW   16        // waves per dist block (1024 threads)
#define GRP_TOTAL (KK / KGRP)            // 256
#define GRP_PER_PHASE (GRP_TOTAL / 2)    // 128
#define GRP_PER_WAVE (GRP_PER_PHASE / NW) // 8

// ---------------------------------------------------------------------------
// Kernel 0: transpose codebook [K][D] -> cbT [D][K] so that for fixed d the
// KGRP values needed are contiguous (enables s_load_dwordx16).
// ---------------------------------------------------------------------------
__global__ __launch_bounds__(256) void vq_transpose(const float* __restrict__ cb,
                                                    float* __restrict__ cbT) {
    __shared__ float t[32][33];
    const int kt = blockIdx.x * 32, dt = blockIdx.y * 32;
    const int tx = threadIdx.x & 31, ty = threadIdx.x >> 5;  // ty 0..7
    #pragma unroll
    for (int r = 0; r < 32; r += 8)
        t[ty + r][tx] = cb[(kt + ty + r) * DD + dt + tx];
    __syncthreads();
    #pragma unroll
    for (int r = 0; r < 32; r += 8)
        cbT[(size_t)(dt + ty + r) * KK + kt + tx] = t[tx][ty + r];
}

// ---------------------------------------------------------------------------
// Kernel 1: codebook squared norms. One wave per codebook row.
// ---------------------------------------------------------------------------
__global__ __launch_bounds__(256) void vq_cnorm(const float* __restrict__ cb,
                                                float* __restrict__ cnorm) {
    int k = (blockIdx.x * 256 + threadIdx.x) >> 6;
    int lane = threadIdx.x & 63;
    float4 v = reinterpret_cast<const float4*>(cb)[k * 64 + lane];
    float s = v.x * v.x + v.y * v.y + v.z * v.z + v.w * v.w;
    #pragma unroll
    for (int off = 32; off > 0; off >>= 1) s += __shfl_xor(s, off, 64);
    if (lane == 0) cnorm[k] = s;
}

// ---------------------------------------------------------------------------
// Kernel 2: distances + per-(block,phase) argmin candidates.
// Block = 1024 threads = 16 waves, owns 64 tokens (lane == token).
// grid.y = 2 phases split K -> 512 blocks -> 2 blocks/CU -> 32 waves/CU.
// x tile in LDS (ds_read_b64/lane); codebook via readfirstlane-forced
// SGPR loads from cbT (s_load_dwordx16) -> inner loop is pure v_fmac.
// ---------------------------------------------------------------------------
__global__ __launch_bounds__(1024, 8) void vq_dist(const float* __restrict__ x,
                                                   const float* __restrict__ cbT,
                                                   const float* __restrict__ cnorm,
                                                   float* __restrict__ cand_d,
                                                   int* __restrict__ cand_k) {
    const int blk = blockIdx.x;
    const int phase = blockIdx.y;
    const int tid = threadIdx.x;
    const int wid = tid >> 6, lane = tid & 63;
    const int b = blk >> 4;
    const int hw0 = (blk & 15) << 6;

    __shared__ alignas(16) float xs[DD * TT];   // 64 KB: [d/2][tok][2]
    __shared__ float bd_s[NW][TT];
    __shared__ int   bk_s[NW][TT];

    // Stage x tile: x[b, d, hw0+i] -> xs[(d/2)*128 + i*2 + (d&1)]
    const float* xb = x + (size_t)b * (DD * HWD) + hw0;
    #pragma unroll
    for (int it = 0; it < 16; ++it) {
        int e = it * 1024 + tid;
        int d = e >> 6, i = e & 63;
        xs[(d >> 1) * 128 + i * 2 + (d & 1)] = xb[d * HWD + i];
    }
    __syncthreads();

    const float2* xs2 = reinterpret_cast<const float2*>(xs) + lane;

    float best = HUGE_VALF;
    int bestk = 0;
    const int g0 = phase * GRP_PER_PHASE + wid * GRP_PER_WAVE;  // contiguous k/wave
    for (int j = 0; j < GRP_PER_WAVE; ++j) {
        // readfirstlane: force wave-uniformity so cbT/cnorm reads scalarize.
        const int k0 = __builtin_amdgcn_readfirstlane((g0 + j) * KGRP);
        const float* __restrict__ cT0 = cbT + k0;
        const float* __restrict__ cn0 = cnorm + k0;
        float acc[KGRP];
        #pragma unroll
        for (int t = 0; t < KGRP; ++t) acc[t] = 0.f;
        #pragma unroll 4
        for (int d2 = 0; d2 < DD / 2; ++d2) {
            float2 xv = xs2[d2 * 64];
            const float* __restrict__ cA = cT0 + (size_t)(2 * d2) * KK;
            const float* __restrict__ cB = cA + KK;
            #pragma unroll
            for (int t = 0; t < KGRP; ++t) acc[t] = fmaf(xv.x, cA[t], acc[t]);
            #pragma unroll
            for (int t = 0; t < KGRP; ++t) acc[t] = fmaf(xv.y, cB[t], acc[t]);
        }
        #pragma unroll
        for (int t = 0; t < KGRP; ++t) {
            // dist = ||c||^2 - 2 x.c  (||x||^2 per-token const, argmin-invariant)
            float dv = fmaf(-2.0f, acc[t], cn0[t]);
            if (dv < best) { best = dv; bestk = k0 + t; }  // k ascending per wave
        }
    }

    bd_s[wid][lane] = best;
    bk_s[wid][lane] = bestk;
    __syncthreads();

    if (tid < TT) {
        float bd = bd_s[0][lane];
        int   bk = bk_s[0][lane];
        #pragma unroll
        for (int w = 1; w < NW; ++w) {
            float dd = bd_s[w][lane];
            int   kw = bk_s[w][lane];
            if (dd < bd || (dd == bd && kw < bk)) { bd = dd; bk = kw; }
        }
        int n = blk * TT + lane;
        cand_d[phase * NTOK + n] = bd;
        cand_k[phase * NTOK + n] = bk;
    }
}

// ---------------------------------------------------------------------------
// Kernel 3: combine 2 phase candidates, gather codebook rows, write
// [B, D, H, W] via LDS transpose (reads AND writes coalesced).
// ---------------------------------------------------------------------------
__global__ __launch_bounds__(256) void vq_gather(const float* __restrict__ cb,
                                                 const float* __restrict__ cand_d,
                                                 const int* __restrict__ cand_k,
                                                 float* __restrict__ out) {
    const int blk = blockIdx.x;
    const int tid = threadIdx.x;
    const int b = blk >> 4;
    const int hw0 = (blk & 15) << 6;

    __shared__ int   bks[TT];
    __shared__ float ts[TT][65];

    if (tid < TT) {
        int n = blk * TT + tid;
        float d0 = cand_d[n];
        int   k0 = cand_k[n];
        float d1 = cand_d[NTOK + n];
        int   k1 = cand_k[NTOK + n];
        bks[tid] = (d1 < d0 || (d1 == d0 && k1 < k0)) ? k1 : k0;
    }
    __syncthreads();

    const int rr = tid >> 6;
    const int j  = tid & 63;
    float* ob = out + (size_t)b * (DD * HWD) + hw0;
    #pragma unroll
    for (int c = 0; c < 4; ++c) {
        const int d0 = c << 6;
        #pragma unroll 4
        for (int it = 0; it < 16; ++it) {
            int tok = it * 4 + rr;
            ts[tok][j] = cb[bks[tok] * DD + d0 + j];
        }
        __syncthreads();
        #pragma unroll 4
        for (int it = 0; it < 16; ++it) {
            int dl = it * 4 + rr;
            ob[(d0 + dl) * HWD + j] = ts[j][dl];
        }
        __syncthreads();
    }
}

// ---------------------------------------------------------------------------
extern "C" void kernel_launch(void* const* d_in, const int* in_sizes, int n_in,
                              void* d_out, int out_size, void* d_ws, size_t ws_size,
                              hipStream_t stream) {
    const float* x  = (const float*)d_in[0];   // [16,256,32,32] f32
    const float* cb = (const float*)d_in[1];   // [4096,256] f32
    float* out = (float*)d_out;                // [16,256,32,32] f32

    float* ws_f   = (float*)d_ws;
    float* cbT    = ws_f;                         // 4096*256 floats (4 MB)
    float* cnorm  = ws_f + KK * DD;               // 4096 floats
    float* cand_d = cnorm + KK;                   // 2 * 16384 floats
    int*   cand_k = (int*)(cand_d + 2 * NTOK);    // 2 * 16384 ints

    vq_transpose<<<dim3(KK / 32, DD / 32), dim3(256), 0, stream>>>(cb, cbT);
    vq_cnorm<<<dim3(KK / 4), dim3(256), 0, stream>>>(cb, cnorm);
    vq_dist<<<dim3(NTOK / TT, 2), dim3(1024), 0, stream>>>(x, cbT, cnorm, cand_d, cand_k);
    vq_gather<<<dim3(NTOK / TT), dim3(256), 0, stream>>>(cb, cand_d, cand_k, out);
}

// Round 3
// 519.833 us; speedup vs baseline: 3.5913x; 1.2502x over previous
//
#include <hip/hip_runtime.h>
#include <math.h>

// Problem: B=16, D=256, H=32, W=32 -> N=16384 tokens; K=4096 codes.
#define DD    256
#define HWD   1024
#define NTOK  16384
#define KK    4096

typedef __attribute__((ext_vector_type(8))) short     bf16x8;
typedef __attribute__((ext_vector_type(4))) float     f32x4;
typedef __attribute__((ext_vector_type(8))) unsigned short ushort8;

// ---- bf16 helpers (RNE, bit-level; no HIP type API dependence) -------------
__device__ __forceinline__ unsigned short f2bf(float f) {
    unsigned u = __float_as_uint(f);
    unsigned r = (u + 0x7FFFu + ((u >> 16) & 1u)) >> 16;
    return (unsigned short)r;
}
__device__ __forceinline__ float bf2f(unsigned short h) {
    return __uint_as_float(((unsigned)h) << 16);
}

#define GLOAD16(gaddr, laddr)                                                   \
    __builtin_amdgcn_global_load_lds(                                           \
        (const __attribute__((address_space(1))) unsigned int*)(gaddr),         \
        (__attribute__((address_space(3))) unsigned int*)(laddr), 16, 0, 0)

// ===========================================================================
// Prep A: x [16,256,1024] f32 -> Ax [16384][768] bf16 triplets (hx, lx, hx)
// ===========================================================================
__global__ __launch_bounds__(256) void vq_splitx(const float* __restrict__ x,
                                                 unsigned short* __restrict__ Ax) {
    const int blk = blockIdx.x;               // 256 blocks
    const int tid = threadIdx.x;
    const int b = blk >> 4;
    const int hw0 = (blk & 15) << 6;

    __shared__ float xls[DD * 64];            // [d][i] 64 KB

    const float* xb = x + (size_t)b * (DD * HWD) + hw0;
    #pragma unroll 8
    for (int it = 0; it < 64; ++it) {
        int e = it * 256 + tid;
        int d = e >> 6, i = e & 63;
        xls[d * 64 + i] = xb[d * HWD + i];
    }
    __syncthreads();

    const int tok_l = tid >> 2;               // 0..63
    const int part  = tid & 3;                // d-range part*64..+64
    const int n = b * HWD + hw0 + tok_l;
    unsigned short* dst = Ax + (size_t)n * 768 + part * 192;

    #pragma unroll
    for (int c8 = 0; c8 < 8; ++c8) {
        const int dbase = part * 64 + c8 * 8;
        ushort8 w0, w1, w2;
        #pragma unroll
        for (int q = 0; q < 8; ++q) {
            float v = xls[(dbase + q) * 64 + tok_l];
            unsigned short hq = f2bf(v);
            unsigned short lq = f2bf(v - bf2f(hq));
            const int i0 = 3 * q, i1 = 3 * q + 1, i2 = 3 * q + 2;
            if (i0 < 8) w0[i0] = hq; else if (i0 < 16) w1[i0 - 8] = hq; else w2[i0 - 16] = hq;
            if (i1 < 8) w0[i1] = lq; else if (i1 < 16) w1[i1 - 8] = lq; else w2[i1 - 16] = lq;
            if (i2 < 8) w0[i2] = hq; else if (i2 < 16) w1[i2 - 8] = hq; else w2[i2 - 16] = hq;
        }
        *(ushort8*)(dst + c8 * 24)      = w0;
        *(ushort8*)(dst + c8 * 24 + 8)  = w1;
        *(ushort8*)(dst + c8 * 24 + 16) = w2;
    }
}

// ===========================================================================
// Prep B: cb [4096][256] f32 -> Bc [4096][768] bf16 triplets (hc, hc, lc)
// ===========================================================================
__global__ __launch_bounds__(256) void vq_splitc(const float* __restrict__ cb,
                                                 unsigned short* __restrict__ Bc) {
    const int gid = blockIdx.x * 256 + threadIdx.x;   // 512 blocks
    const int k = gid >> 5;
    const int j = gid & 31;                           // 8 d's per thread
    const float4* cb4 = (const float4*)cb;
    float4 a = cb4[k * 64 + j * 2];
    float4 bq = cb4[k * 64 + j * 2 + 1];
    float vv[8] = {a.x, a.y, a.z, a.w, bq.x, bq.y, bq.z, bq.w};
    ushort8 w0, w1, w2;
    #pragma unroll
    for (int q = 0; q < 8; ++q) {
        unsigned short hq = f2bf(vv[q]);
        unsigned short lq = f2bf(vv[q] - bf2f(hq));
        const int i0 = 3 * q, i1 = 3 * q + 1, i2 = 3 * q + 2;
        if (i0 < 8) w0[i0] = hq; else if (i0 < 16) w1[i0 - 8] = hq; else w2[i0 - 16] = hq;
        if (i1 < 8) w0[i1] = hq; else if (i1 < 16) w1[i1 - 8] = hq; else w2[i1 - 16] = hq;
        if (i2 < 8) w0[i2] = lq; else if (i2 < 16) w1[i2 - 8] = lq; else w2[i2 - 16] = lq;
    }
    unsigned short* dst = Bc + (size_t)k * 768 + j * 24;
    *(ushort8*)(dst)      = w0;
    *(ushort8*)(dst + 8)  = w1;
    *(ushort8*)(dst + 16) = w2;
}

// ===========================================================================
// cbT [256][4096] transpose (for exact fallback + small-ws path)
// ===========================================================================
__global__ __launch_bounds__(256) void vq_transpose(const float* __restrict__ cb,
                                                    float* __restrict__ cbT) {
    __shared__ float t[32][33];
    const int kt = blockIdx.x * 32, dt = blockIdx.y * 32;
    const int tx = threadIdx.x & 31, ty = threadIdx.x >> 5;
    #pragma unroll
    for (int r = 0; r < 32; r += 8)
        t[ty + r][tx] = cb[(kt + ty + r) * DD + dt + tx];
    __syncthreads();
    #pragma unroll
    for (int r = 0; r < 32; r += 8)
        cbT[(size_t)(dt + ty + r) * KK + kt + tx] = t[tx][ty + r];
}

// ===========================================================================
// cnorm: exact fp32 row norms of cb (same code as rounds 1-2, bit-proven)
// ===========================================================================
__global__ __launch_bounds__(256) void vq_cnorm(const float* __restrict__ cb,
                                                float* __restrict__ cnorm) {
    int k = (blockIdx.x * 256 + threadIdx.x) >> 6;
    int lane = threadIdx.x & 63;
    float4 v = reinterpret_cast<const float4*>(cb)[k * 64 + lane];
    float s = v.x * v.x + v.y * v.y + v.z * v.z + v.w * v.w;
    #pragma unroll
    for (int off = 32; off > 0; off >>= 1) s += __shfl_xor(s, off, 64);
    if (lane == 0) cnorm[k] = s;
}

__global__ void vq_zero(int* cnt) { if (threadIdx.x == 0) *cnt = 0; }

// ===========================================================================
// MFMA GEMM + fused running (best, second, argmin).
// M=16384, Ncodes=4096 (NPH=4 phases of 1024), Kred=768 bf16.
// Block: 256 thr = 4 waves (2Mx2N), tile 128x128, wave tile 64x64 (4x4 frags).
// ===========================================================================
#define BM 128
#define BN 128
#define BK 64
#define KRED 768
#define NPH 4
#define NT_PER_PH 8
#define MARGIN 0.05f

__global__ __launch_bounds__(256, 2) void vq_gemm_min(
    const unsigned short* __restrict__ Ax,
    const unsigned short* __restrict__ Bc,
    const float* __restrict__ cnorm,
    float* __restrict__ candb, float* __restrict__ cands, int* __restrict__ candk)
{
    const int tid  = threadIdx.x;
    const int wid  = tid >> 6, lane = tid & 63;
    const int wm   = wid >> 1, wn = wid & 1;
    const int l15  = lane & 15, l4 = lane >> 4;
    const int mblk = blockIdx.x;       // 0..127
    const int phase = blockIdx.y;      // 0..3

    __shared__ alignas(16) unsigned short As[BM * BK];  // 16 KB, [row][k] linear
    __shared__ alignas(16) unsigned short Bs[BN * BK];  // 16 KB
    __shared__ float mrg[BM][2][3];                     // [row][wn][b,s,kbits]

    float runb[16], runs[16];
    int   runk[16];
    #pragma unroll
    for (int e = 0; e < 16; ++e) { runb[e] = 3.0e38f; runs[e] = 3.0e38f; runk[e] = 0; }

    const int stage_row = (lane >> 3);          // 0..7
    const int stage_c16 = (lane & 7);           // 16B column

    for (int nt = 0; nt < NT_PER_PH; ++nt) {
        f32x4 acc[4][4];
        #pragma unroll
        for (int mi = 0; mi < 4; ++mi)
            #pragma unroll
            for (int ni = 0; ni < 4; ++ni)
                acc[mi][ni] = (f32x4){0.f, 0.f, 0.f, 0.f};

        for (int kk = 0; kk < KRED / BK; ++kk) {   // 12
            __syncthreads();
            // stage A+B slices [128][64] via global_load_lds (16B/lane)
            #pragma unroll
            for (int ib = 0; ib < 4; ++ib) {
                const int rb = wid * 32 + ib * 8;
                const int ldsoff = __builtin_amdgcn_readfirstlane(rb * 64);
                const int rA = rb + stage_row;
                GLOAD16(Ax + (size_t)(mblk * BM + rA) * KRED + kk * BK + stage_c16 * 8,
                        &As[ldsoff]);
                GLOAD16(Bc + (size_t)(phase * 1024 + nt * BN + rA) * KRED + kk * BK + stage_c16 * 8,
                        &Bs[ldsoff]);
            }
            __syncthreads();

            #pragma unroll
            for (int kh = 0; kh < 2; ++kh) {
                bf16x8 af[4], bfr[4];
                #pragma unroll
                for (int mi = 0; mi < 4; ++mi) {
                    int r = wm * 64 + mi * 16 + l15;
                    af[mi] = *(const bf16x8*)&As[r * BK + kh * 32 + l4 * 8];
                }
                #pragma unroll
                for (int ni = 0; ni < 4; ++ni) {
                    int c = wn * 64 + ni * 16 + l15;
                    bfr[ni] = *(const bf16x8*)&Bs[c * BK + kh * 32 + l4 * 8];
                }
                #pragma unroll
                for (int mi = 0; mi < 4; ++mi)
                    #pragma unroll
                    for (int ni = 0; ni < 4; ++ni)
                        acc[mi][ni] = __builtin_amdgcn_mfma_f32_16x16x32_bf16(
                            af[mi], bfr[ni], acc[mi][ni], 0, 0, 0);
            }
        }

        // epilogue: distances + running (best, second, k); k ascending order.
        #pragma unroll
        for (int ni = 0; ni < 4; ++ni) {
            const int c = phase * 1024 + nt * BN + wn * 64 + ni * 16 + l15;
            const float cn = cnorm[c];
            #pragma unroll
            for (int mi = 0; mi < 4; ++mi) {
                #pragma unroll
                for (int rg = 0; rg < 4; ++rg) {
                    float d = fmaf(-2.0f, acc[mi][ni][rg], cn);
                    const int e = mi * 4 + rg;
                    float ob = runb[e];
                    runs[e] = fminf(fmaxf(d, ob), runs[e]);   // med3(d, ob, runs)
                    runk[e] = (d < ob) ? c : runk[e];
                    runb[e] = fminf(d, ob);
                }
            }
        }
    }

    // cross-lane reduce within each 16-lane row-group
    #pragma unroll
    for (int e = 0; e < 16; ++e) {
        float b = runb[e], s = runs[e];
        int   k = runk[e];
        #pragma unroll
        for (int off = 1; off < 16; off <<= 1) {
            float ob = __shfl_xor(b, off, 64);
            float os = __shfl_xor(s, off, 64);
            int   ok = __shfl_xor(k, off, 64);
            float nb = fminf(b, ob);
            s = fminf(fminf(s, os), fmaxf(b, ob));
            k = (ob < b) ? ok : k;      // exact ties get flagged anyway
            b = nb;
        }
        if (l15 == 0) {
            int row = wm * 64 + (e >> 2) * 16 + l4 * 4 + (e & 3);
            mrg[row][wn][0] = b;
            mrg[row][wn][1] = s;
            mrg[row][wn][2] = __int_as_float(k);
        }
    }
    __syncthreads();

    if (tid < BM) {
        const int row = tid;
        float b0 = mrg[row][0][0], s0 = mrg[row][0][1];
        float b1 = mrg[row][1][0], s1 = mrg[row][1][1];
        int   k0 = __float_as_int(mrg[row][0][2]);
        int   k1 = __float_as_int(mrg[row][1][2]);
        float b = fminf(b0, b1);
        float s = fminf(fminf(s0, s1), fmaxf(b0, b1));
        int   k = (b1 < b0) ? k1 : k0;
        const int tok = mblk * BM + row;
        candb[phase * NTOK + tok] = b;
        cands[phase * NTOK + tok] = s;
        candk[phase * NTOK + tok] = k;
    }
}

// ===========================================================================
// merge phases -> out_k; flag tokens with approx gap < MARGIN
// ===========================================================================
__global__ __launch_bounds__(256) void vq_merge(
    const float* __restrict__ candb, const float* __restrict__ cands,
    const int* __restrict__ candk, int* __restrict__ out_k,
    int* __restrict__ flagged, int* __restrict__ cnt)
{
    const int tok = blockIdx.x * 256 + threadIdx.x;
    float b = candb[tok], s = cands[tok];
    int   k = candk[tok];
    #pragma unroll
    for (int p = 1; p < NPH; ++p) {
        float pb = candb[p * NTOK + tok], ps = cands[p * NTOK + tok];
        int   pk = candk[p * NTOK + tok];
        float nb = fminf(b, pb);
        s = fminf(fminf(s, ps), fmaxf(b, pb));
        k = (pb < b) ? pk : k;
        b = nb;
    }
    out_k[tok] = k;
    if (s - b < MARGIN) {
        int i = atomicAdd(cnt, 1);
        flagged[i] = tok;
    }
}

// ===========================================================================
// exact fp32 fallback for flagged tokens (replays round-2's bit-exact chain)
// ===========================================================================
__global__ __launch_bounds__(256) void vq_exact(
    const float* __restrict__ x, const float* __restrict__ cbT,
    const float* __restrict__ cnorm, const int* __restrict__ flagged,
    const int* __restrict__ cnt, int* __restrict__ out_k)
{
    __shared__ float xs[4][DD];
    __shared__ float bd[256];
    __shared__ int   bk[256];
    const int tid = threadIdx.x;
    const int n = *cnt;

    for (int base = blockIdx.x * 4; base < n; base += gridDim.x * 4) {
        const int ntok = min(4, n - base);
        #pragma unroll
        for (int s = 0; s < 4; ++s) {
            if (s < ntok) {
                int tok = flagged[base + s];
                int b = tok >> 10, hw = tok & 1023;
                xs[s][tid] = x[(size_t)b * (DD * HWD) + tid * HWD + hw];
            }
        }
        __syncthreads();

        float acc[4][4][4];   // [token][chunk][i]
        #pragma unroll
        for (int s = 0; s < 4; ++s)
            #pragma unroll
            for (int ch = 0; ch < 4; ++ch)
                #pragma unroll
                for (int i = 0; i < 4; ++i) acc[s][ch][i] = 0.f;

        for (int d = 0; d < DD; ++d) {
            float xv0 = xs[0][d], xv1 = xs[1][d], xv2 = xs[2][d], xv3 = xs[3][d];
            #pragma unroll
            for (int ch = 0; ch < 4; ++ch) {
                float4 ct = *(const float4*)(cbT + (size_t)d * KK + ch * 1024 + tid * 4);
                float cv[4] = {ct.x, ct.y, ct.z, ct.w};
                #pragma unroll
                for (int i = 0; i < 4; ++i) {
                    acc[0][ch][i] = fmaf(xv0, cv[i], acc[0][ch][i]);
                    acc[1][ch][i] = fmaf(xv1, cv[i], acc[1][ch][i]);
                    acc[2][ch][i] = fmaf(xv2, cv[i], acc[2][ch][i]);
                    acc[3][ch][i] = fmaf(xv3, cv[i], acc[3][ch][i]);
                }
            }
        }

        for (int s = 0; s < 4; ++s) {
            if (s >= ntok) break;
            float best = 3.0e38f;
            int   bkk = 0;
            #pragma unroll
            for (int ch = 0; ch < 4; ++ch) {
                #pragma unroll
                for (int i = 0; i < 4; ++i) {
                    int k = ch * 1024 + tid * 4 + i;
                    float dd = fmaf(-2.0f, acc[s][ch][i], cnorm[k]);
                    if (dd < best) { best = dd; bkk = k; }   // ascending k
                }
            }
            bd[tid] = best; bk[tid] = bkk;
            __syncthreads();
            for (int w = 128; w >= 1; w >>= 1) {
                if (tid < w) {
                    float o = bd[tid + w]; int ok = bk[tid + w];
                    if (o < bd[tid] || (o == bd[tid] && ok < bk[tid])) { bd[tid] = o; bk[tid] = ok; }
                }
                __syncthreads();
            }
            if (tid == 0) out_k[flagged[base + s]] = bk[0];
            __syncthreads();
        }
        __syncthreads();
    }
}

// ===========================================================================
// gather + transposed coalesced write (round-2 structure, input = out_k)
// ===========================================================================
__global__ __launch_bounds__(256) void vq_gather(const float* __restrict__ cb,
                                                 const int* __restrict__ out_k,
                                                 float* __restrict__ out) {
    const int blk = blockIdx.x;
    const int tid = threadIdx.x;
    const int b = blk >> 4;
    const int hw0 = (blk & 15) << 6;

    __shared__ int   bks[64];
    __shared__ float ts[64][65];

    if (tid < 64) bks[tid] = out_k[blk * 64 + tid];
    __syncthreads();

    const int rr = tid >> 6;
    const int j  = tid & 63;
    float* ob = out + (size_t)b * (DD * HWD) + hw0;
    #pragma unroll
    for (int c = 0; c < 4; ++c) {
        const int d0 = c << 6;
        #pragma unroll 4
        for (int it = 0; it < 16; ++it) {
            int tok = it * 4 + rr;
            ts[tok][j] = cb[bks[tok] * DD + d0 + j];
        }
        __syncthreads();
        #pragma unroll 4
        for (int it = 0; it < 16; ++it) {
            int dl = it * 4 + rr;
            ob[(d0 + dl) * HWD + j] = ts[j][dl];
        }
        __syncthreads();
    }
}

// ===========================================================================
// Small-ws fallback path: round-2 proven kernels
// ===========================================================================
#define TT2   64
#define KGRP2 16
#define NW2   16
__global__ __launch_bounds__(1024, 8) void vq_dist2(const float* __restrict__ x,
                                                    const float* __restrict__ cbT,
                                                    const float* __restrict__ cnorm,
                                                    float* __restrict__ cand_d,
                                                    int* __restrict__ cand_k) {
    const int blk = blockIdx.x;
    const int phase = blockIdx.y;
    const int tid = threadIdx.x;
    const int wid = tid >> 6, lane = tid & 63;
    const int b = blk >> 4;
    const int hw0 = (blk & 15) << 6;

    __shared__ alignas(16) float xs[DD * TT2];
    __shared__ float bd_s[NW2][TT2];
    __shared__ int   bk_s[NW2][TT2];

    const float* xb = x + (size_t)b * (DD * HWD) + hw0;
    #pragma unroll
    for (int it = 0; it < 16; ++it) {
        int e = it * 1024 + tid;
        int d = e >> 6, i = e & 63;
        xs[(d >> 1) * 128 + i * 2 + (d & 1)] = xb[d * HWD + i];
    }
    __syncthreads();

    const float2* xs2 = reinterpret_cast<const float2*>(xs) + lane;
    float best = 3.0e38f;
    int bestk = 0;
    const int g0 = phase * 128 + wid * 8;
    for (int j = 0; j < 8; ++j) {
        const int k0 = __builtin_amdgcn_readfirstlane((g0 + j) * KGRP2);
        const float* __restrict__ cT0 = cbT + k0;
        const float* __restrict__ cn0 = cnorm + k0;
        float acc[KGRP2];
        #pragma unroll
        for (int t = 0; t < KGRP2; ++t) acc[t] = 0.f;
        #pragma unroll 4
        for (int d2 = 0; d2 < DD / 2; ++d2) {
            float2 xv = xs2[d2 * 64];
            const float* __restrict__ cA = cT0 + (size_t)(2 * d2) * KK;
            const float* __restrict__ cB = cA + KK;
            #pragma unroll
            for (int t = 0; t < KGRP2; ++t) acc[t] = fmaf(xv.x, cA[t], acc[t]);
            #pragma unroll
            for (int t = 0; t < KGRP2; ++t) acc[t] = fmaf(xv.y, cB[t], acc[t]);
        }
        #pragma unroll
        for (int t = 0; t < KGRP2; ++t) {
            float dv = fmaf(-2.0f, acc[t], cn0[t]);
            if (dv < best) { best = dv; bestk = k0 + t; }
        }
    }
    bd_s[wid][lane] = best;
    bk_s[wid][lane] = bestk;
    __syncthreads();
    if (tid < TT2) {
        float bdv = bd_s[0][lane];
        int   bkv = bk_s[0][lane];
        #pragma unroll
        for (int w = 1; w < NW2; ++w) {
            float ddv = bd_s[w][lane];
            int   kw = bk_s[w][lane];
            if (ddv < bdv || (ddv == bdv && kw < bkv)) { bdv = ddv; bkv = kw; }
        }
        int nn = blk * TT2 + lane;
        cand_d[phase * NTOK + nn] = bdv;
        cand_k[phase * NTOK + nn] = bkv;
    }
}

__global__ __launch_bounds__(256) void vq_merge2(const float* __restrict__ cand_d,
                                                 const int* __restrict__ cand_k,
                                                 int* __restrict__ out_k) {
    const int tok = blockIdx.x * 256 + threadIdx.x;
    float d0 = cand_d[tok]; int k0 = cand_k[tok];
    float d1 = cand_d[NTOK + tok]; int k1 = cand_k[NTOK + tok];
    out_k[tok] = (d1 < d0 || (d1 == d0 && k1 < k0)) ? k1 : k0;
}

// ===========================================================================
extern "C" void kernel_launch(void* const* d_in, const int* in_sizes, int n_in,
                              void* d_out, int out_size, void* d_ws, size_t ws_size,
                              hipStream_t stream) {
    const float* x  = (const float*)d_in[0];
    const float* cb = (const float*)d_in[1];
    float* out = (float*)d_out;

    char* w = (char*)d_ws;
    float* cbT    = (float*)(w);                       // 4 MB
    float* cnorm  = (float*)(w + 4194304);             // 16 KB
    int*   out_k  = (int*)  (w + 4210688);             // 64 KB
    int*   cnt    = (int*)  (w + 4276224);             // 256 B
    int*   flagged= (int*)  (w + 4276480);             // 64 KB
    float* candb  = (float*)(w + 4342016);             // 256 KB
    float* cands  = (float*)(w + 4604160);             // 256 KB
    int*   candk  = (int*)  (w + 4866304);             // 256 KB
    unsigned short* Ax = (unsigned short*)(w + 5128448);   // 24 MB
    unsigned short* Bc = (unsigned short*)(w + 30294272);  // 6 MB
    const size_t BIG_NEED = 36585728;

    vq_transpose<<<dim3(KK / 32, DD / 32), dim3(256), 0, stream>>>(cb, cbT);
    vq_cnorm<<<dim3(KK / 4), dim3(256), 0, stream>>>(cb, cnorm);

    if (ws_size >= BIG_NEED) {
        vq_splitx<<<dim3(256), dim3(256), 0, stream>>>(x, Ax);
        vq_splitc<<<dim3(512), dim3(256), 0, stream>>>(cb, Bc);
        vq_zero<<<dim3(1), dim3(64), 0, stream>>>(cnt);
        vq_gemm_min<<<dim3(NTOK / BM, NPH), dim3(256), 0, stream>>>(
            Ax, Bc, cnorm, candb, cands, candk);
        vq_merge<<<dim3(NTOK / 256), dim3(256), 0, stream>>>(
            candb, cands, candk, out_k, flagged, cnt);
        vq_exact<<<dim3(128), dim3(256), 0, stream>>>(
            x, cbT, cnorm, flagged, cnt, out_k);
    } else {
        // proven round-2 path (needs ~4.4 MB)
        float* cand_d = candb;   // reuse slots (fit below 4.87 MB + 256 KB)
        int*   cand_k = candk;
        vq_dist2<<<dim3(NTOK / TT2, 2), dim3(1024), 0, stream>>>(
            x, cbT, cnorm, cand_d, cand_k);
        vq_merge2<<<dim3(NTOK / 256), dim3(256), 0, stream>>>(cand_d, cand_k, out_k);
    }
    vq_gather<<<dim3(NTOK / 64), dim3(256), 0, stream>>>(cb, out_k, out);
}

// Round 5
// 280.871 us; speedup vs baseline: 6.6466x; 1.8508x over previous
//
#include <hip/hip_runtime.h>
#include <math.h>

// Problem: B=16, D=256, H=32, W=32 -> N=16384 tokens; K=4096 codes.
#define DD    256
#define HWD   1024
#define NTOK  16384
#define KK    4096

typedef __attribute__((ext_vector_type(8))) short     bf16x8;
typedef __attribute__((ext_vector_type(4))) float     f32x4;
typedef __attribute__((ext_vector_type(8))) unsigned short ushort8;

// ---- bf16 helpers (RNE, bit-level) ----------------------------------------
__device__ __forceinline__ unsigned short f2bf(float f) {
    unsigned u = __float_as_uint(f);
    unsigned r = (u + 0x7FFFu + ((u >> 16) & 1u)) >> 16;
    return (unsigned short)r;
}
__device__ __forceinline__ float bf2f(unsigned short h) {
    return __uint_as_float(((unsigned)h) << 16);
}

#define GLOAD16(gaddr, laddr)                                                   \
    __builtin_amdgcn_global_load_lds(                                           \
        (const __attribute__((address_space(1))) unsigned int*)(gaddr),         \
        (__attribute__((address_space(3))) unsigned int*)(laddr), 16, 0, 0)

// ===========================================================================
// Prep A: x [16,256,1024] f32 -> Ax [16384][768] bf16 triplets (hx, lx, hx)
// ===========================================================================
__global__ __launch_bounds__(256) void vq_splitx(const float* __restrict__ x,
                                                 unsigned short* __restrict__ Ax) {
    const int blk = blockIdx.x;               // 256 blocks
    const int tid = threadIdx.x;
    const int b = blk >> 4;
    const int hw0 = (blk & 15) << 6;

    __shared__ float xls[DD * 64];            // [d][i] 64 KB

    const float* xb = x + (size_t)b * (DD * HWD) + hw0;
    #pragma unroll 8
    for (int it = 0; it < 64; ++it) {
        int e = it * 256 + tid;
        int d = e >> 6, i = e & 63;
        xls[d * 64 + i] = xb[d * HWD + i];
    }
    __syncthreads();

    const int tok_l = tid >> 2;               // 0..63
    const int part  = tid & 3;                // d-range part*64..+64
    const int n = b * HWD + hw0 + tok_l;
    unsigned short* dst = Ax + (size_t)n * 768 + part * 192;

    #pragma unroll
    for (int c8 = 0; c8 < 8; ++c8) {
        const int dbase = part * 64 + c8 * 8;
        ushort8 w0, w1, w2;
        #pragma unroll
        for (int q = 0; q < 8; ++q) {
            float v = xls[(dbase + q) * 64 + tok_l];
            unsigned short hq = f2bf(v);
            unsigned short lq = f2bf(v - bf2f(hq));
            const int i0 = 3 * q, i1 = 3 * q + 1, i2 = 3 * q + 2;
            if (i0 < 8) w0[i0] = hq; else if (i0 < 16) w1[i0 - 8] = hq; else w2[i0 - 16] = hq;
            if (i1 < 8) w0[i1] = lq; else if (i1 < 16) w1[i1 - 8] = lq; else w2[i1 - 16] = lq;
            if (i2 < 8) w0[i2] = hq; else if (i2 < 16) w1[i2 - 8] = hq; else w2[i2 - 16] = hq;
        }
        *(ushort8*)(dst + c8 * 24)      = w0;
        *(ushort8*)(dst + c8 * 24 + 8)  = w1;
        *(ushort8*)(dst + c8 * 24 + 16) = w2;
    }
}

// ===========================================================================
// Prep B: cb [4096][256] f32 -> Bc [4096][768] bf16 triplets (hc, hc, lc)
// ===========================================================================
__global__ __launch_bounds__(256) void vq_splitc(const float* __restrict__ cb,
                                                 unsigned short* __restrict__ Bc) {
    const int gid = blockIdx.x * 256 + threadIdx.x;   // 512 blocks
    const int k = gid >> 5;
    const int j = gid & 31;                           // 8 d's per thread
    const float4* cb4 = (const float4*)cb;
    float4 a = cb4[k * 64 + j * 2];
    float4 bq = cb4[k * 64 + j * 2 + 1];
    float vv[8] = {a.x, a.y, a.z, a.w, bq.x, bq.y, bq.z, bq.w};
    ushort8 w0, w1, w2;
    #pragma unroll
    for (int q = 0; q < 8; ++q) {
        unsigned short hq = f2bf(vv[q]);
        unsigned short lq = f2bf(vv[q] - bf2f(hq));
        const int i0 = 3 * q, i1 = 3 * q + 1, i2 = 3 * q + 2;
        if (i0 < 8) w0[i0] = hq; else if (i0 < 16) w1[i0 - 8] = hq; else w2[i0 - 16] = hq;
        if (i1 < 8) w0[i1] = hq; else if (i1 < 16) w1[i1 - 8] = hq; else w2[i1 - 16] = hq;
        if (i2 < 8) w0[i2] = lq; else if (i2 < 16) w1[i2 - 8] = lq; else w2[i2 - 16] = lq;
    }
    unsigned short* dst = Bc + (size_t)k * 768 + j * 24;
    *(ushort8*)(dst)      = w0;
    *(ushort8*)(dst + 8)  = w1;
    *(ushort8*)(dst + 16) = w2;
}

// ===========================================================================
// cbT [256][4096] transpose
// ===========================================================================
__global__ __launch_bounds__(256) void vq_transpose(const float* __restrict__ cb,
                                                    float* __restrict__ cbT) {
    __shared__ float t[32][33];
    const int kt = blockIdx.x * 32, dt = blockIdx.y * 32;
    const int tx = threadIdx.x & 31, ty = threadIdx.x >> 5;
    #pragma unroll
    for (int r = 0; r < 32; r += 8)
        t[ty + r][tx] = cb[(kt + ty + r) * DD + dt + tx];
    __syncthreads();
    #pragma unroll
    for (int r = 0; r < 32; r += 8)
        cbT[(size_t)(dt + ty + r) * KK + kt + tx] = t[tx][ty + r];
}

// ===========================================================================
// cnorm: exact fp32 row norms of cb
// ===========================================================================
__global__ __launch_bounds__(256) void vq_cnorm(const float* __restrict__ cb,
                                                float* __restrict__ cnorm) {
    int k = (blockIdx.x * 256 + threadIdx.x) >> 6;
    int lane = threadIdx.x & 63;
    float4 v = reinterpret_cast<const float4*>(cb)[k * 64 + lane];
    float s = v.x * v.x + v.y * v.y + v.z * v.z + v.w * v.w;
    #pragma unroll
    for (int off = 32; off > 0; off >>= 1) s += __shfl_xor(s, off, 64);
    if (lane == 0) cnorm[k] = s;
}

__global__ void vq_zero(int* cnt) { if (threadIdx.x == 0) *cnt = 0; }

// ===========================================================================
// MFMA GEMM + fused running (best, second, argmin).
// ===========================================================================
#define BM 128
#define BN 128
#define BK 64
#define KRED 768
#define NPH 4
#define NT_PER_PH 8
#define MARGIN 0.05f

__global__ __launch_bounds__(256, 2) void vq_gemm_min(
    const unsigned short* __restrict__ Ax,
    const unsigned short* __restrict__ Bc,
    const float* __restrict__ cnorm,
    float* __restrict__ candb, float* __restrict__ cands, int* __restrict__ candk)
{
    const int tid  = threadIdx.x;
    const int wid  = tid >> 6, lane = tid & 63;
    const int wm   = wid >> 1, wn = wid & 1;
    const int l15  = lane & 15, l4 = lane >> 4;
    const int mblk = blockIdx.x;       // 0..127
    const int phase = blockIdx.y;      // 0..3

    __shared__ alignas(16) unsigned short As[BM * BK];  // 16 KB linear [row][k]
    __shared__ alignas(16) unsigned short Bs[BN * BK];  // 16 KB
    __shared__ float mrg[BM][2][3];

    float runb[16], runs[16];
    int   runk[16];
    #pragma unroll
    for (int e = 0; e < 16; ++e) { runb[e] = 3.0e38f; runs[e] = 3.0e38f; runk[e] = 0; }

    const int stage_row = (lane >> 3);          // 0..7
    const int stage_c16 = (lane & 7);           // 16B column

    for (int nt = 0; nt < NT_PER_PH; ++nt) {
        f32x4 acc[4][4];
        #pragma unroll
        for (int mi = 0; mi < 4; ++mi)
            #pragma unroll
            for (int ni = 0; ni < 4; ++ni)
                acc[mi][ni] = (f32x4){0.f, 0.f, 0.f, 0.f};

        for (int kk = 0; kk < KRED / BK; ++kk) {   // 12
            __syncthreads();
            #pragma unroll
            for (int ib = 0; ib < 4; ++ib) {
                const int rb = wid * 32 + ib * 8;
                const int ldsoff = __builtin_amdgcn_readfirstlane(rb * 64);
                const int rA = rb + stage_row;
                GLOAD16(Ax + (size_t)(mblk * BM + rA) * KRED + kk * BK + stage_c16 * 8,
                        &As[ldsoff]);
                GLOAD16(Bc + (size_t)(phase * 1024 + nt * BN + rA) * KRED + kk * BK + stage_c16 * 8,
                        &Bs[ldsoff]);
            }
            __syncthreads();

            #pragma unroll
            for (int kh = 0; kh < 2; ++kh) {
                bf16x8 af[4], bfr[4];
                #pragma unroll
                for (int mi = 0; mi < 4; ++mi) {
                    int r = wm * 64 + mi * 16 + l15;
                    af[mi] = *(const bf16x8*)&As[r * BK + kh * 32 + l4 * 8];
                }
                #pragma unroll
                for (int ni = 0; ni < 4; ++ni) {
                    int c = wn * 64 + ni * 16 + l15;
                    bfr[ni] = *(const bf16x8*)&Bs[c * BK + kh * 32 + l4 * 8];
                }
                #pragma unroll
                for (int mi = 0; mi < 4; ++mi)
                    #pragma unroll
                    for (int ni = 0; ni < 4; ++ni)
                        acc[mi][ni] = __builtin_amdgcn_mfma_f32_16x16x32_bf16(
                            af[mi], bfr[ni], acc[mi][ni], 0, 0, 0);
            }
        }

        #pragma unroll
        for (int ni = 0; ni < 4; ++ni) {
            const int c = phase * 1024 + nt * BN + wn * 64 + ni * 16 + l15;
            const float cn = cnorm[c];
            #pragma unroll
            for (int mi = 0; mi < 4; ++mi) {
                #pragma unroll
                for (int rg = 0; rg < 4; ++rg) {
                    float d = fmaf(-2.0f, acc[mi][ni][rg], cn);
                    const int e = mi * 4 + rg;
                    float ob = runb[e];
                    runs[e] = fminf(fmaxf(d, ob), runs[e]);
                    runk[e] = (d < ob) ? c : runk[e];
                    runb[e] = fminf(d, ob);
                }
            }
        }
    }

    #pragma unroll
    for (int e = 0; e < 16; ++e) {
        float b = runb[e], s = runs[e];
        int   k = runk[e];
        #pragma unroll
        for (int off = 1; off < 16; off <<= 1) {
            float ob = __shfl_xor(b, off, 64);
            float os = __shfl_xor(s, off, 64);
            int   ok = __shfl_xor(k, off, 64);
            float nb = fminf(b, ob);
            s = fminf(fminf(s, os), fmaxf(b, ob));
            k = (ob < b) ? ok : k;
            b = nb;
        }
        if (l15 == 0) {
            int row = wm * 64 + (e >> 2) * 16 + l4 * 4 + (e & 3);
            mrg[row][wn][0] = b;
            mrg[row][wn][1] = s;
            mrg[row][wn][2] = __int_as_float(k);
        }
    }
    __syncthreads();

    if (tid < BM) {
        const int row = tid;
        float b0 = mrg[row][0][0], s0 = mrg[row][0][1];
        float b1 = mrg[row][1][0], s1 = mrg[row][1][1];
        int   k0 = __float_as_int(mrg[row][0][2]);
        int   k1 = __float_as_int(mrg[row][1][2]);
        float b = fminf(b0, b1);
        float s = fminf(fminf(s0, s1), fmaxf(b0, b1));
        int   k = (b1 < b0) ? k1 : k0;
        const int tok = mblk * BM + row;
        candb[phase * NTOK + tok] = b;
        cands[phase * NTOK + tok] = s;
        candk[phase * NTOK + tok] = k;
    }
}

// ===========================================================================
// merge phases -> out_k; flag tokens with approx gap < MARGIN, init packed
// ===========================================================================
__global__ __launch_bounds__(256) void vq_merge(
    const float* __restrict__ candb, const float* __restrict__ cands,
    const int* __restrict__ candk, int* __restrict__ out_k,
    int* __restrict__ flagged, int* __restrict__ cnt,
    unsigned long long* __restrict__ packed)
{
    const int tok = blockIdx.x * 256 + threadIdx.x;
    float b = candb[tok], s = cands[tok];
    int   k = candk[tok];
    #pragma unroll
    for (int p = 1; p < NPH; ++p) {
        float pb = candb[p * NTOK + tok], ps = cands[p * NTOK + tok];
        int   pk = candk[p * NTOK + tok];
        float nb = fminf(b, pb);
        s = fminf(fminf(s, ps), fmaxf(b, pb));
        k = (pb < b) ? pk : k;
        b = nb;
    }
    out_k[tok] = k;
    if (s - b < MARGIN) {
        int i = atomicAdd(cnt, 1);
        flagged[i] = tok;
        packed[i] = 0xFFFFFFFFFFFFFFFFull;
    }
}

// ===========================================================================
// exact fp32 fallback, PARALLEL: work item = (flagged token, 1024-code chunk).
// Grid-strided over 1024 blocks; block reduces its chunk, atomicMin-publishes
// packed (orderable-dist << 32 | k)  -> min dist, tie -> smaller k (== numpy).
// ===========================================================================
__global__ __launch_bounds__(256) void vq_exact(
    const float* __restrict__ x, const float* __restrict__ cbT,
    const float* __restrict__ cnorm, const int* __restrict__ flagged,
    const int* __restrict__ cnt, unsigned long long* __restrict__ packed)
{
    const int tid = threadIdx.x;
    const int lane = tid & 63, wid = tid >> 6;
    const int items = (*cnt) << 2;
    __shared__ float xs[DD];
    __shared__ unsigned long long wbest[4];

    for (int w = blockIdx.x; w < items; w += gridDim.x) {
        const int ti = w >> 2;
        const int ch = w & 3;
        const int tok = flagged[ti];
        const int b = tok >> 10, hw = tok & 1023;
        __syncthreads();
        xs[tid] = x[(size_t)b * (DD * HWD) + tid * HWD + hw];
        __syncthreads();

        const int kbase = ch * 1024 + tid * 4;
        float a0 = 0.f, a1 = 0.f, a2 = 0.f, a3 = 0.f;
        #pragma unroll 8
        for (int d = 0; d < DD; ++d) {
            const float xv = xs[d];
            const float4 cv = *(const float4*)(cbT + (size_t)d * KK + kbase);
            a0 = fmaf(xv, cv.x, a0);
            a1 = fmaf(xv, cv.y, a1);
            a2 = fmaf(xv, cv.z, a2);
            a3 = fmaf(xv, cv.w, a3);
        }
        float d0 = fmaf(-2.f, a0, cnorm[kbase]);
        float d1 = fmaf(-2.f, a1, cnorm[kbase + 1]);
        float d2 = fmaf(-2.f, a2, cnorm[kbase + 2]);
        float d3 = fmaf(-2.f, a3, cnorm[kbase + 3]);
        float best = d0; int bk = kbase;
        if (d1 < best) { best = d1; bk = kbase + 1; }
        if (d2 < best) { best = d2; bk = kbase + 2; }
        if (d3 < best) { best = d3; bk = kbase + 3; }
        unsigned ub = __float_as_uint(best);
        ub = (ub & 0x80000000u) ? ~ub : (ub | 0x80000000u);   // order-preserving
        unsigned long long pk = ((unsigned long long)ub << 32) | (unsigned)bk;
        #pragma unroll
        for (int off = 1; off < 64; off <<= 1) {
            unsigned long long o = __shfl_xor(pk, off, 64);
            pk = (o < pk) ? o : pk;
        }
        if (lane == 0) wbest[wid] = pk;
        __syncthreads();
        if (tid == 0) {
            unsigned long long m = wbest[0];
            #pragma unroll
            for (int i = 1; i < 4; ++i) m = (wbest[i] < m) ? wbest[i] : m;
            atomicMin(&packed[ti], m);
        }
    }
}

__global__ __launch_bounds__(256) void vq_unpack(
    const int* __restrict__ flagged, const int* __restrict__ cnt,
    const unsigned long long* __restrict__ packed, int* __restrict__ out_k)
{
    const int i = blockIdx.x * 256 + threadIdx.x;
    if (i < *cnt) out_k[flagged[i]] = (int)(packed[i] & 0xFFFFFFFFull);
}

// ===========================================================================
// gather + transposed coalesced write
// ===========================================================================
__global__ __launch_bounds__(256) void vq_gather(const float* __restrict__ cb,
                                                 const int* __restrict__ out_k,
                                                 float* __restrict__ out) {
    const int blk = blockIdx.x;
    const int tid = threadIdx.x;
    const int b = blk >> 4;
    const int hw0 = (blk & 15) << 6;

    __shared__ int   bks[64];
    __shared__ float ts[64][65];

    if (tid < 64) bks[tid] = out_k[blk * 64 + tid];
    __syncthreads();

    const int rr = tid >> 6;
    const int j  = tid & 63;
    float* ob = out + (size_t)b * (DD * HWD) + hw0;
    #pragma unroll
    for (int c = 0; c < 4; ++c) {
        const int d0 = c << 6;
        #pragma unroll 4
        for (int it = 0; it < 16; ++it) {
            int tok = it * 4 + rr;
            ts[tok][j] = cb[bks[tok] * DD + d0 + j];
        }
        __syncthreads();
        #pragma unroll 4
        for (int it = 0; it < 16; ++it) {
            int dl = it * 4 + rr;
            ob[(d0 + dl) * HWD + j] = ts[j][dl];
        }
        __syncthreads();
    }
}

// ===========================================================================
// Small-ws fallback path (round-2 proven)
// ===========================================================================
#define TT2   64
#define KGRP2 16
#define NW2   16
__global__ __launch_bounds__(1024, 8) void vq_dist2(const float* __restrict__ x,
                                                    const float* __restrict__ cbT,
                                                    const float* __restrict__ cnorm,
                                                    float* __restrict__ cand_d,
                                                    int* __restrict__ cand_k) {
    const int blk = blockIdx.x;
    const int phase = blockIdx.y;
    const int tid = threadIdx.x;
    const int wid = tid >> 6, lane = tid & 63;
    const int b = blk >> 4;
    const int hw0 = (blk & 15) << 6;

    __shared__ alignas(16) float xs[DD * TT2];
    __shared__ float bd_s[NW2][TT2];
    __shared__ int   bk_s[NW2][TT2];

    const float* xb = x + (size_t)b * (DD * HWD) + hw0;
    #pragma unroll
    for (int it = 0; it < 16; ++it) {
        int e = it * 1024 + tid;
        int d = e >> 6, i = e & 63;
        xs[(d >> 1) * 128 + i * 2 + (d & 1)] = xb[d * HWD + i];
    }
    __syncthreads();

    const float2* xs2 = reinterpret_cast<const float2*>(xs) + lane;
    float best = 3.0e38f;
    int bestk = 0;
    const int g0 = phase * 128 + wid * 8;
    for (int j = 0; j < 8; ++j) {
        const int k0 = __builtin_amdgcn_readfirstlane((g0 + j) * KGRP2);
        const float* __restrict__ cT0 = cbT + k0;
        const float* __restrict__ cn0 = cnorm + k0;
        float acc[KGRP2];
        #pragma unroll
        for (int t = 0; t < KGRP2; ++t) acc[t] = 0.f;
        #pragma unroll 4
        for (int d2 = 0; d2 < DD / 2; ++d2) {
            float2 xv = xs2[d2 * 64];
            const float* __restrict__ cA = cT0 + (size_t)(2 * d2) * KK;
            const float* __restrict__ cB = cA + KK;
            #pragma unroll
            for (int t = 0; t < KGRP2; ++t) acc[t] = fmaf(xv.x, cA[t], acc[t]);
            #pragma unroll
            for (int t = 0; t < KGRP2; ++t) acc[t] = fmaf(xv.y, cB[t], acc[t]);
        }
        #pragma unroll
        for (int t = 0; t < KGRP2; ++t) {
            float dv = fmaf(-2.0f, acc[t], cn0[t]);
            if (dv < best) { best = dv; bestk = k0 + t; }
        }
    }
    bd_s[wid][lane] = best;
    bk_s[wid][lane] = bestk;
    __syncthreads();
    if (tid < TT2) {
        float bdv = bd_s[0][lane];
        int   bkv = bk_s[0][lane];
        #pragma unroll
        for (int w = 1; w < NW2; ++w) {
            float ddv = bd_s[w][lane];
            int   kw = bk_s[w][lane];
            if (ddv < bdv || (ddv == bdv && kw < bkv)) { bdv = ddv; bkv = kw; }
        }
        int nn = blk * TT2 + lane;
        cand_d[phase * NTOK + nn] = bdv;
        cand_k[phase * NTOK + nn] = bkv;
    }
}

__global__ __launch_bounds__(256) void vq_merge2(const float* __restrict__ cand_d,
                                                 const int* __restrict__ cand_k,
                                                 int* __restrict__ out_k) {
    const int tok = blockIdx.x * 256 + threadIdx.x;
    float d0 = cand_d[tok]; int k0 = cand_k[tok];
    float d1 = cand_d[NTOK + tok]; int k1 = cand_k[NTOK + tok];
    out_k[tok] = (d1 < d0 || (d1 == d0 && k1 < k0)) ? k1 : k0;
}

// ===========================================================================
extern "C" void kernel_launch(void* const* d_in, const int* in_sizes, int n_in,
                              void* d_out, int out_size, void* d_ws, size_t ws_size,
                              hipStream_t stream) {
    const float* x  = (const float*)d_in[0];
    const float* cb = (const float*)d_in[1];
    float* out = (float*)d_out;

    char* w = (char*)d_ws;
    float* cbT    = (float*)(w);                       // 4 MB
    float* cnorm  = (float*)(w + 4194304);             // 16 KB
    int*   out_k  = (int*)  (w + 4210688);             // 64 KB
    int*   cnt    = (int*)  (w + 4276224);             // 256 B
    int*   flagged= (int*)  (w + 4276480);             // 64 KB
    float* candb  = (float*)(w + 4342016);             // 256 KB
    float* cands  = (float*)(w + 4604160);             // 256 KB
    int*   candk  = (int*)  (w + 4866304);             // 256 KB
    unsigned long long* packed = (unsigned long long*)(w + 5128448); // 128 KB
    unsigned short* Ax = (unsigned short*)(w + 5259520);   // 24 MB
    unsigned short* Bc = (unsigned short*)(w + 30425344);  // 6 MB
    const size_t BIG_NEED = 36716800;

    vq_transpose<<<dim3(KK / 32, DD / 32), dim3(256), 0, stream>>>(cb, cbT);
    vq_cnorm<<<dim3(KK / 4), dim3(256), 0, stream>>>(cb, cnorm);

    if (ws_size >= BIG_NEED) {
        vq_splitx<<<dim3(256), dim3(256), 0, stream>>>(x, Ax);
        vq_splitc<<<dim3(512), dim3(256), 0, stream>>>(cb, Bc);
        vq_zero<<<dim3(1), dim3(64), 0, stream>>>(cnt);
        vq_gemm_min<<<dim3(NTOK / BM, NPH), dim3(256), 0, stream>>>(
            Ax, Bc, cnorm, candb, cands, candk);
        vq_merge<<<dim3(NTOK / 256), dim3(256), 0, stream>>>(
            candb, cands, candk, out_k, flagged, cnt, packed);
        vq_exact<<<dim3(1024), dim3(256), 0, stream>>>(
            x, cbT, cnorm, flagged, cnt, packed);
        vq_unpack<<<dim3(NTOK / 256), dim3(256), 0, stream>>>(
            flagged, cnt, packed, out_k);
    } else {
        float* cand_d = candb;
        int*   cand_k = candk;
        vq_dist2<<<dim3(NTOK / TT2, 2), dim3(1024), 0, stream>>>(
            x, cbT, cnorm, cand_d, cand_k);
        vq_merge2<<<dim3(NTOK / 256), dim3(256), 0, stream>>>(cand_d, cand_k, out_k);
    }
    vq_gather<<<dim3(NTOK / 64), dim3(256), 0, stream>>>(cb, out_k, out);
}